// Round 5
// baseline (319.768 us; speedup 1.0000x reference)
//
#include <hip/hip_runtime.h>

// x: (64, 8192, 256) float32, cumsum along dim 1.
#define BATCH 64
#define LEN   8192
#define DIM   256
#define D4    (DIM / 4)        // 64 float4 per row
#define Q     16               // channel slices per batch (one block each)
#define SF4   (D4 / Q)         // 4 float4 per slice (16 channels, 64 B/row)
#define R     4                // rows per thread per tile
#define GROUPS 64              // row-groups per tile (256 threads / 4 f4)
#define TILE  (GROUPS * R)     // 256 rows per tile
#define NT    (LEN / TILE)     // 32 tiles, serial per block (carry in regs)
#define LGW   16               // local groups per wave (64 lanes / 4)

typedef float vf4 __attribute__((ext_vector_type(4)));

__device__ __forceinline__ void f4_add(float4& a, const float4& v) {
    a.x += v.x; a.y += v.y; a.z += v.z; a.w += v.w;
}

// One block owns the full 8192-row chain of a (batch, 16-channel slice).
// Serial over 32 tiles of 256 rows; carry in registers; x read once, out once.
// Tile scan: 4-row thread sum -> wave shfl-scan over 16 local groups ->
// tiny LDS exchange of 4 wave totals (parity double-buffer, 1 sync/tile).
__global__ __launch_bounds__(256, 4) void chained_scan_kernel(
    const float* __restrict__ x, float* __restrict__ out)
{
    __shared__ float4 wtot[2][4][SF4];   // [parity][wave][f4] = 512 B

    const int q    = blockIdx.x;         // channel slice
    const int b    = blockIdx.y;         // batch
    const int t    = threadIdx.x;        // 0..255
    const int f    = t & (SF4 - 1);      // f4 within slice (0..3)
    const int g    = t >> 2;             // group within tile (0..63), 4 rows each
    const int lane = t & 63;
    const int w    = t >> 6;             // wave 0..3
    const int lg   = lane >> 2;          // local group within wave (0..15)

    const size_t chain = (size_t)b * LEN * D4 + (size_t)q * SF4 + f;
    const float4* xp = reinterpret_cast<const float4*>(x) + chain;
    float4*       op = reinterpret_cast<float4*>(out) + chain;
    const size_t r0 = (size_t)(g * R) * D4;  // thread's first row offset in a tile

    float4 carry = make_float4(0.f, 0.f, 0.f, 0.f);

    // Prefetch tile 0.
    float4 a[R];
#pragma unroll
    for (int r = 0; r < R; ++r) a[r] = xp[r0 + (size_t)r * D4];

    for (int tile = 0; tile < NT; ++tile) {
        // Issue next tile's loads first; HBM latency hides under tile body.
        const int nxt = (tile + 1 < NT) ? tile + 1 : tile;
        const size_t nb = (size_t)nxt * TILE * D4 + r0;
        float4 nx[R];
#pragma unroll
        for (int r = 0; r < R; ++r) nx[r] = xp[nb + (size_t)r * D4];

        // 4-row group sum.
        float4 ls = a[0];
        f4_add(ls, a[1]); f4_add(ls, a[2]); f4_add(ls, a[3]);

        // Wave-inclusive scan over the 16 local groups (same-f lanes, stride 4).
        float4 incl = ls;
#pragma unroll
        for (int d = 1; d < LGW; d <<= 1) {
            float4 o;
            o.x = __shfl_up(incl.x, d * SF4, 64);
            o.y = __shfl_up(incl.y, d * SF4, 64);
            o.z = __shfl_up(incl.z, d * SF4, 64);
            o.w = __shfl_up(incl.w, d * SF4, 64);
            if (lg >= d) f4_add(incl, o);
        }

        // Publish per-wave totals (last local group holds them), parity-buffered.
        const int par = tile & 1;
        if (lane >= 60) wtot[par][w][f] = incl;
        __syncthreads();

        // Cross-wave exclusive prefix + tile total (4 broadcast reads).
        float4 cross = make_float4(0.f, 0.f, 0.f, 0.f);
        float4 tot   = make_float4(0.f, 0.f, 0.f, 0.f);
#pragma unroll
        for (int ww = 0; ww < 4; ++ww) {
            float4 s = wtot[par][ww][f];
            if (ww < w) f4_add(cross, s);
            f4_add(tot, s);
        }

        // acc = carry + exclusive-prefix-of-this-group = carry + cross + incl - ls
        float4 acc = carry;
        f4_add(acc, cross);
        f4_add(acc, incl);
        acc.x -= ls.x; acc.y -= ls.y; acc.z -= ls.z; acc.w -= ls.w;

        // Emit 4 output rows (nontemporal: out never re-read; keep L3 for x).
        const size_t ob = (size_t)tile * TILE * D4 + r0;
#pragma unroll
        for (int r = 0; r < R; ++r) {
            f4_add(acc, a[r]);
            __builtin_nontemporal_store(*reinterpret_cast<const vf4*>(&acc),
                                        reinterpret_cast<vf4*>(op + ob + (size_t)r * D4));
        }

        f4_add(carry, tot);
#pragma unroll
        for (int r = 0; r < R; ++r) a[r] = nx[r];
    }
}

extern "C" void kernel_launch(void* const* d_in, const int* in_sizes, int n_in,
                              void* d_out, int out_size, void* d_ws, size_t ws_size,
                              hipStream_t stream) {
    const float* x = (const float*)d_in[0];
    float* out = (float*)d_out;
    chained_scan_kernel<<<dim3(Q, BATCH), 256, 0, stream>>>(x, out);
}

// Round 6
// 229.267 us; speedup vs baseline: 1.3947x; 1.3947x over previous
//
#include <hip/hip_runtime.h>

// x: (64, 8192, 256) float32, cumsum along dim 1.
#define BATCH 64
#define LEN   8192
#define DIM   256
#define D4    (DIM / 4)        // 64 float4 per row
#define Q     8                // channel slices per batch (128 B/row slice = 1 cache line)
#define SF4   (D4 / Q)         // 8 float4 per slice
#define NTHR  512
#define R     4                // rows per thread per tile
#define GROUPS (NTHR / SF4)    // 64 row-groups per tile
#define TILE  (GROUPS * R)     // 256 rows per tile
#define NT    (LEN / TILE)     // 32 tiles, serial per block (carry in regs)
#define NWAVES (NTHR / 64)     // 8

typedef float vf4 __attribute__((ext_vector_type(4)));

__device__ __forceinline__ void f4_add(float4& a, const float4& v) {
    a.x += v.x; a.y += v.y; a.z += v.z; a.w += v.w;
}

// One block owns the full 8192-row chain of a (batch, 32-channel slice).
// Serial over 32 tiles of 256 rows; carry in registers; x read once, out once.
// Tile scan: 4-row thread sum -> wave shfl-scan over 8 local groups ->
// LDS exchange of 8 wave totals (parity double-buffer, 1 sync/tile).
__global__ __launch_bounds__(NTHR, 2) void chained_scan_kernel(
    const float* __restrict__ x, float* __restrict__ out)
{
    __shared__ float4 wtot[2][NWAVES][SF4];   // 2 KiB

    const int q    = blockIdx.x;         // channel slice
    const int b    = blockIdx.y;         // batch
    const int t    = threadIdx.x;        // 0..511
    const int f    = t & (SF4 - 1);      // f4 within slice (0..7)
    const int g    = t >> 3;             // group within tile (0..63), 4 rows each
    const int lane = t & 63;
    const int w    = t >> 6;             // wave 0..7
    const int lg   = lane >> 3;          // local group within wave (0..7)

    const size_t chain = (size_t)b * LEN * D4 + (size_t)q * SF4 + f;
    const float4* xp = reinterpret_cast<const float4*>(x) + chain;
    float4*       op = reinterpret_cast<float4*>(out) + chain;
    const size_t r0 = (size_t)(g * R) * D4;  // thread's first row offset in a tile

    float4 carry = make_float4(0.f, 0.f, 0.f, 0.f);

    // Prefetch tile 0.
    float4 a[R];
#pragma unroll
    for (int r = 0; r < R; ++r) a[r] = xp[r0 + (size_t)r * D4];

    for (int tile = 0; tile < NT; ++tile) {
        // Issue next tile's loads first; HBM latency hides under tile body.
        const int nxt = (tile + 1 < NT) ? tile + 1 : tile;
        const size_t nb = (size_t)nxt * TILE * D4 + r0;
        float4 nx[R];
#pragma unroll
        for (int r = 0; r < R; ++r) nx[r] = xp[nb + (size_t)r * D4];

        // 4-row group sum.
        float4 ls = a[0];
        f4_add(ls, a[1]); f4_add(ls, a[2]); f4_add(ls, a[3]);

        // Wave-inclusive scan over the 8 local groups (same-f lanes, stride 8).
        float4 incl = ls;
#pragma unroll
        for (int d = 1; d < 8; d <<= 1) {
            float4 o;
            o.x = __shfl_up(incl.x, d * SF4, 64);
            o.y = __shfl_up(incl.y, d * SF4, 64);
            o.z = __shfl_up(incl.z, d * SF4, 64);
            o.w = __shfl_up(incl.w, d * SF4, 64);
            if (lg >= d) f4_add(incl, o);
        }

        // Publish per-wave totals (last local group holds them), parity-buffered.
        const int par = tile & 1;
        if (lane >= 56) wtot[par][w][f] = incl;
        __syncthreads();

        // Cross-wave exclusive prefix + tile total (8 broadcast reads).
        float4 cross = make_float4(0.f, 0.f, 0.f, 0.f);
        float4 tot   = make_float4(0.f, 0.f, 0.f, 0.f);
#pragma unroll
        for (int ww = 0; ww < NWAVES; ++ww) {
            float4 s = wtot[par][ww][f];
            if (ww < w) f4_add(cross, s);
            f4_add(tot, s);
        }

        // acc = carry + exclusive-prefix-of-this-group = carry + cross + incl - ls
        float4 acc = carry;
        f4_add(acc, cross);
        f4_add(acc, incl);
        acc.x -= ls.x; acc.y -= ls.y; acc.z -= ls.z; acc.w -= ls.w;

        // Emit 4 output rows (nontemporal: out never re-read; keep L3 for x).
        const size_t ob = (size_t)tile * TILE * D4 + r0;
#pragma unroll
        for (int r = 0; r < R; ++r) {
            f4_add(acc, a[r]);
            __builtin_nontemporal_store(*reinterpret_cast<const vf4*>(&acc),
                                        reinterpret_cast<vf4*>(op + ob + (size_t)r * D4));
        }

        f4_add(carry, tot);
#pragma unroll
        for (int r = 0; r < R; ++r) a[r] = nx[r];
    }
}

extern "C" void kernel_launch(void* const* d_in, const int* in_sizes, int n_in,
                              void* d_out, int out_size, void* d_ws, size_t ws_size,
                              hipStream_t stream) {
    const float* x = (const float*)d_in[0];
    float* out = (float*)d_out;
    chained_scan_kernel<<<dim3(Q, BATCH), NTHR, 0, stream>>>(x, out);
}